// Round 5
// baseline (365.941 us; speedup 1.0000x reference)
//
#include <hip/hip_runtime.h>
#include <math.h>

#define B_ 16
#define H_ 224
#define W_ 224
#define HP_ 226
#define WP_ 226
#define CIN_ 3
#define COUT_ 64
#define NPIX_ (B_ * H_ * W_)      /* 802816 */
#define NPAD_ (B_ * HP_ * WP_)    /* 817216 */
#define NBLK2_ (NPIX_ / 512)      /* 1568: 2 pixels per thread */
#define MAXNORM_ 0.999f
#define MINN_ 1e-7f
#define TCL_ (1.0f - 1e-5f)
#define LCLAMP_ 3.8002012f        /* atanh(0.999) */
#define BN_EPS_ 1e-5f
#define NF_ ((float)NPIX_)
/* Half-tile LDS row stride (floats): 32 ch + 4 pad = 36 = 9 quads (odd).
   b128 write: lane start-bank (36*lane)%32 -> 2x per 4-bank group = floor.
   b128 transposed read (rb): 8 distinct groups per 8-lane phase = floor. */
#define PADW2_ 36

typedef float v4f __attribute__((ext_vector_type(4)));

// R5 theory: R1-R4 all pinned the conv kernels at ~120-135us (VALUBusy 20%,
// HBM 40%, MfmaUtil 0) regardless of occupancy/spill/LDS shape. The shared
// cost: 432 wave-uniform 16B weight fetches per thread, scalarized into
// s_load batches with lgkmcnt waits between every batch and its FMA cluster
// (SGPR_Count=112). Fix: weights live in LDS (uniform-address ds_read
// broadcast, LDS pipe overlaps VALU) and each thread computes 2 pixels so
// every weight read feeds 2 FMA quads.
struct Acc8 { v4f v0, v1, v2, v3, v4, v5, v6, v7; };
#define EACH8(X) X(0) X(1) X(2) X(3) X(4) X(5) X(6) X(7)

// ---------------------------------------------------------------------------
// K0: x (NCHW f32) -> u0p (padded NHWC4): u0 = logmap0(projx(x)) per pixel,
// zero halo ring. atanh(t) = 0.5*log((1+t)/(1-t)) via v_log_f32.
// ---------------------------------------------------------------------------
__global__ void k0_transform(const float* __restrict__ x, float4* __restrict__ u0p) {
  int idx = blockIdx.x * 256 + threadIdx.x;
  if (idx >= NPAD_) return;
  int b = idx / (HP_ * WP_);
  int r = idx % (HP_ * WP_);
  int yp = r / WP_, xp = r % WP_;
  float4 o = make_float4(0.f, 0.f, 0.f, 0.f);
  if (yp >= 1 && yp <= H_ && xp >= 1 && xp <= W_) {
    const float* xb = x + (size_t)b * (CIN_ * H_ * W_) + (size_t)(yp - 1) * W_ + (xp - 1);
    float v0 = xb[0];
    float v1 = xb[H_ * W_];
    float v2 = xb[2 * H_ * W_];
    // projx
    float n = sqrtf(fmaf(v0, v0, fmaf(v1, v1, v2 * v2)));
    float ncl = fmaxf(n, MINN_);
    float s = fminf(1.0f, MAXNORM_ / ncl);
    float p0 = v0 * s, p1 = v1 * s, p2 = v2 * s;
    // logmap0
    float np_ = fmaxf(sqrtf(fmaf(p0, p0, fmaf(p1, p1, p2 * p2))), MINN_);
    float t = fminf(np_, TCL_);
    float ath = 0.5f * __logf(__fdividef(1.0f + t, 1.0f - t));
    float f = __fdividef(ath, np_);
    o.x = p0 * f; o.y = p1 * f; o.z = p2 * f;
  }
  u0p[idx] = o;
}

// ---------------------------------------------------------------------------
// Paired half-conv: output channels [32h,32h+32) for TWO pixels. Weights come
// from LDS (wq, quad layout tap*48 + cin*16 + q, uniform-address broadcast);
// each weight read feeds both pixels' FMAs. Tap loads are per-instruction
// contiguous 16B x 64 lanes (L1-hot across taps/halves).
// ---------------------------------------------------------------------------
__device__ __forceinline__ void conv_pair_half(
    const float4* __restrict__ u0p, const v4f* __restrict__ wq,
    const v4f* __restrict__ bq, int px0, int px1, int h,
    Acc8& a0, Acc8& a1) {
  int b0 = px0 / (H_ * W_), r0 = px0 % (H_ * W_);
  int y0 = r0 / W_, x0 = r0 % W_;
  int b1 = px1 / (H_ * W_), r1 = px1 % (H_ * W_);
  int y1 = r1 / W_, x1 = r1 % W_;
  const float4* base0 = u0p + ((size_t)b0 * HP_ + y0) * WP_ + x0;
  const float4* base1 = u0p + ((size_t)b1 * HP_ + y1) * WP_ + x1;
  int h8 = h * 8;
#define INIT(i) { v4f bv = bq[h8 + i]; a0.v##i = bv; a1.v##i = bv; }
  EACH8(INIT)
#undef INIT
#define FX(i) { v4f w = wp[i];      a0.v##i += in0.x * w; a1.v##i += in1.x * w; }
#define FY(i) { v4f w = wp[16 + i]; a0.v##i += in0.y * w; a1.v##i += in1.y * w; }
#define FZ(i) { v4f w = wp[32 + i]; a0.v##i += in0.z * w; a1.v##i += in1.z * w; }
#define TAP(t) { float4 in0 = base0[((t) / 3) * WP_ + ((t) % 3)];            \
                 float4 in1 = base1[((t) / 3) * WP_ + ((t) % 3)];            \
                 const v4f* wp = wq + (t) * 48 + h8;                         \
                 EACH8(FX) EACH8(FY) EACH8(FZ) }
  TAP(0) TAP(1) TAP(2) TAP(3) TAP(4) TAP(5) TAP(6) TAP(7) TAP(8)
#undef TAP
#undef FX
#undef FY
#undef FZ
}

__device__ __forceinline__ v4f vshfl_xor(v4f v, int m) {
  v4f r;
  r.x = __shfl_xor(v.x, m, 64);
  r.y = __shfl_xor(v.y, m, 64);
  r.z = __shfl_xor(v.z, m, 64);
  r.w = __shfl_xor(v.w, m, 64);
  return r;
}
__device__ __forceinline__ v4f vrelu(v4f v) {
  v.x = fmaxf(v.x, 0.f); v.y = fmaxf(v.y, 0.f);
  v.z = fmaxf(v.z, 0.f); v.w = fmaxf(v.w, 0.f);
  return v;
}
__device__ __forceinline__ float hsum(v4f v) { return (v.x + v.y) + (v.z + v.w); }

// staging a whole Acc8 into this thread's tile row (named members only)
#define STAGE8(acc) do {                                                     \
  *(v4f*)(row + 0)  = acc.v0; *(v4f*)(row + 4)  = acc.v1;                    \
  *(v4f*)(row + 8)  = acc.v2; *(v4f*)(row + 12) = acc.v3;                    \
  *(v4f*)(row + 16) = acc.v4; *(v4f*)(row + 20) = acc.v5;                    \
  *(v4f*)(row + 24) = acc.v6; *(v4f*)(row + 28) = acc.v7;                    \
} while (0)

// ---------------------------------------------------------------------------
// K1: ONE conv pass for stats. Per thread: 2 pixels (S0 = blk*512+t,
// S1 = +256). conv half-A pair -> stage S0's A; conv half-B pair -> clamp
// scales sc0/sc1 (need full 64-ch norms); then 4 stage/read rounds through
// the wave-private tile (A0,A1,B0,B1), each transposed read applying sc[row]
// and accumulating per-channel sum/sumsq; fold once at the end.
// ---------------------------------------------------------------------------
__global__ void __launch_bounds__(256, 3)
k1_stats(const float4* __restrict__ u0p, const float* __restrict__ wgt,
         const float* __restrict__ bias, float* __restrict__ partials) {
  __shared__ __align__(16) float stg[4 * 64 * PADW2_];  // 36,864 B
  __shared__ __align__(16) v4f wlds[432];               //  6,912 B
  __shared__ __align__(16) v4f blds[16];                //    256 B
  __shared__ float scl[512];                            //  2,048 B
  __shared__ float red_s[256], red_q[256];              //  2,048 B
  int tid = threadIdx.x;
  {
    const v4f* wg = (const v4f*)wgt;
    wlds[tid] = wg[tid];
    if (tid < 176) wlds[256 + tid] = wg[256 + tid];
    if (tid < 16) blds[tid] = ((const v4f*)bias)[tid];
  }
  __syncthreads();

  int px0 = blockIdx.x * 512 + tid;
  int px1 = px0 + 256;
  int lane = tid & 63, wid = tid >> 6;
  float* row = stg + (size_t)(wid * 64 + lane) * PADW2_;
  int pr8 = lane >> 3, qi = lane & 7;
  const float* rb = stg + (size_t)wid * 64 * PADW2_ + pr8 * PADW2_ + qi * 4;
  const float* sc_s0 = scl + wid * 64;
  const float* sc_s1 = scl + 256 + wid * 64;

  // ---- half A (ch 0..31) for both pixels ----
  Acc8 xA0, xA1;
  conv_pair_half(u0p, wlds, blds, px0, px1, 0, xA0, xA1);
  v4f t0 = (v4f)0.0f, t1 = (v4f)0.0f;
#define SQ2(i) { t0 += xA0.v##i * xA0.v##i; t1 += xA1.v##i * xA1.v##i; }
  EACH8(SQ2)
#undef SQ2
  float s20 = hsum(t0), s21 = hsum(t1);
  STAGE8(xA0);
  __builtin_amdgcn_wave_barrier();

  // ---- half B (ch 32..63), finish clamp scales ----
  Acc8 xB0, xB1;
  conv_pair_half(u0p, wlds, blds, px0, px1, 1, xB0, xB1);
  t0 = (v4f)0.0f; t1 = (v4f)0.0f;
#define SQ2(i) { t0 += xB0.v##i * xB0.v##i; t1 += xB1.v##i * xB1.v##i; }
  EACH8(SQ2)
#undef SQ2
  s20 += hsum(t0); s21 += hsum(t1);
  float n0 = sqrtf(s20), n1 = sqrtf(s21);
  scl[wid * 64 + lane]       = (n0 > LCLAMP_) ? (LCLAMP_ / n0) : 1.0f;
  scl[256 + wid * 64 + lane] = (n1 > LCLAMP_) ? (LCLAMP_ / n1) : 1.0f;
  __builtin_amdgcn_wave_barrier();

  v4f sA = (v4f)0.0f, qA = (v4f)0.0f, sB = (v4f)0.0f, qB = (v4f)0.0f;
#define READROUND(sv, qv, scp)                                               \
  _Pragma("unroll") for (int j = 0; j < 8; j++) {                            \
    float g = (scp)[j * 8 + pr8];                                            \
    v4f v = *(const v4f*)(rb + j * 8 * PADW2_) * g;                          \
    sv += v; qv += v * v;                                                    \
  }
  // round A0 (tile = xA0, S0)
  READROUND(sA, qA, sc_s0)
  __builtin_amdgcn_wave_barrier();
  STAGE8(xA1);
  __builtin_amdgcn_wave_barrier();
  READROUND(sA, qA, sc_s1)
  __builtin_amdgcn_wave_barrier();
  STAGE8(xB0);
  __builtin_amdgcn_wave_barrier();
  READROUND(sB, qB, sc_s0)
  __builtin_amdgcn_wave_barrier();
  STAGE8(xB1);
  __builtin_amdgcn_wave_barrier();
  READROUND(sB, qB, sc_s1)
#undef READROUND

  sA += vshfl_xor(sA, 8);  qA += vshfl_xor(qA, 8);
  sA += vshfl_xor(sA, 16); qA += vshfl_xor(qA, 16);
  sA += vshfl_xor(sA, 32); qA += vshfl_xor(qA, 32);
  sB += vshfl_xor(sB, 8);  qB += vshfl_xor(qB, 8);
  sB += vshfl_xor(sB, 16); qB += vshfl_xor(qB, 16);
  sB += vshfl_xor(sB, 32); qB += vshfl_xor(qB, 32);
  if (lane < 8) {  // lane qi holds wave-total for ch quad qi
    *(v4f*)&red_s[wid * 32 + qi * 4] = sA;
    *(v4f*)&red_q[wid * 32 + qi * 4] = qA;
    *(v4f*)&red_s[128 + wid * 32 + qi * 4] = sB;
    *(v4f*)&red_q[128 + wid * 32 + qi * 4] = qB;
  }
  __syncthreads();
  if (tid < 128) {
    int c = tid & 63;
    int base = (c >> 5) * 128 + (c & 31);
    const float* rr = (tid < 64) ? red_s : red_q;
    float tot = rr[base] + rr[base + 32] + rr[base + 64] + rr[base + 96];
    // partials[blk*128 + c] = sum_c ; partials[blk*128 + 64 + c] = sumsq_c
    partials[(size_t)blockIdx.x * 128 + tid] = tot;
  }
}

// ---------------------------------------------------------------------------
// K2: 64 blocks, one per channel. Block c reduces the sum and sumsq columns
// of partials[1568][128] and writes mean[c], rstd*gamma[c].
// ---------------------------------------------------------------------------
__global__ void k2_finalize(const float* __restrict__ partials, const float* __restrict__ gamma,
                            float* __restrict__ stats) {
  int c = blockIdx.x;      // 0..63
  int t = threadIdx.x;     // 256 threads
  float s = 0.f, q = 0.f;
  for (int i = t; i < NBLK2_; i += 256) {
    s += partials[(size_t)i * 128 + c];
    q += partials[(size_t)i * 128 + 64 + c];
  }
  __shared__ float ls[256], lq[256];
  ls[t] = s; lq[t] = q;
  __syncthreads();
#pragma unroll
  for (int off = 128; off > 0; off >>= 1) {
    if (t < off) { ls[t] += ls[t + off]; lq[t] += lq[t + off]; }
    __syncthreads();
  }
  if (t == 0) {
    float mean = ls[0] / NF_;
    float msq  = lq[0] / NF_;
    float var = msq - mean * mean;            // jnp.var (ddof=0)
    stats[c] = mean;
    stats[64 + c] = gamma[c] / sqrtf(var + BN_EPS_);
  }
}

// per-pixel output scale: folds clamp+relu-norm+tanh expmap+projx into one g
__device__ __forceinline__ float out_scale(float nv2, float r2) {
  float nv = sqrtf(nv2);
  float sv = (nv > LCLAMP_) ? (LCLAMP_ / nv) : 1.0f;  // logmap0(expmap0(v))
  float nw = fmaxf(sv * sqrtf(r2), MINN_);
  float e2 = __expf(2.0f * nw);                        // tanh via v_exp_f32
  float th = 1.0f - __fdividef(2.0f, e2 + 1.0f);
  float se = __fdividef(th, nw);
  float clip = fminf(1.0f, MAXNORM_ / fmaxf(th, MINN_));
  return se * clip * sv;
}

// ---------------------------------------------------------------------------
// K3: second conv pass + BN + folded nonlinear tail (out = g * relu(u),
// g = fs*sv since relu(sv*u) = sv*relu(u), sv>0). 2 pixels/thread, weights
// from LDS, 4 stage/store rounds through the wave-private tile; stores are
// coalesced nontemporal b128 (8 x 128B full-sector runs per instruction).
// ---------------------------------------------------------------------------
__global__ void __launch_bounds__(256, 3)
k3_final(const float4* __restrict__ u0p, const float* __restrict__ wgt,
         const float* __restrict__ bias, const float* __restrict__ stats,
         const float* __restrict__ beta, float* __restrict__ out) {
  __shared__ __align__(16) float stg[4 * 64 * PADW2_];  // 36,864 B
  __shared__ __align__(16) v4f wlds[432];
  __shared__ __align__(16) v4f blds[16];
  __shared__ __align__(16) v4f m4[16], rg4[16], bt4[16];
  __shared__ float gl[512];
  int tid = threadIdx.x;
  {
    const v4f* wg = (const v4f*)wgt;
    wlds[tid] = wg[tid];
    if (tid < 176) wlds[256 + tid] = wg[256 + tid];
    if (tid < 16) {
      blds[tid] = ((const v4f*)bias)[tid];
      m4[tid]   = ((const v4f*)stats)[tid];
      rg4[tid]  = ((const v4f*)(stats + 64))[tid];
      bt4[tid]  = ((const v4f*)beta)[tid];
    }
  }
  __syncthreads();

  int px0 = blockIdx.x * 512 + tid;
  int px1 = px0 + 256;
  int lane = tid & 63, wid = tid >> 6;
  float* row = stg + (size_t)(wid * 64 + lane) * PADW2_;
  int pr8 = lane >> 3, qi = lane & 7;
  const float* rb = stg + (size_t)wid * 64 * PADW2_ + pr8 * PADW2_ + qi * 4;
  const float* gl_s0 = gl + wid * 64;
  const float* gl_s1 = gl + 256 + wid * 64;
  v4f* outw0 = (v4f*)out + ((size_t)blockIdx.x * 512 + wid * 64) * 16;
  v4f* outw1 = outw0 + (size_t)256 * 16;

  // ---- half A (ch 0..31): conv pair + BN, accumulate nv2 / r2 ----
  Acc8 xA0, xA1;
  conv_pair_half(u0p, wlds, blds, px0, px1, 0, xA0, xA1);
  v4f sa0 = (v4f)0.0f, ra0 = (v4f)0.0f, sa1 = (v4f)0.0f, ra1 = (v4f)0.0f;
#define BNA(i) {                                                             \
    xA0.v##i = (xA0.v##i - m4[i]) * rg4[i] + bt4[i];                         \
    sa0 += xA0.v##i * xA0.v##i; v4f r_ = vrelu(xA0.v##i); ra0 += r_ * r_;    \
    xA1.v##i = (xA1.v##i - m4[i]) * rg4[i] + bt4[i];                         \
    sa1 += xA1.v##i * xA1.v##i; v4f p_ = vrelu(xA1.v##i); ra1 += p_ * p_; }
  EACH8(BNA)
#undef BNA
  STAGE8(xA0);
  __builtin_amdgcn_wave_barrier();

  // ---- half B (ch 32..63): conv pair + BN, finish per-pixel scalars ----
  Acc8 xB0, xB1;
  conv_pair_half(u0p, wlds, blds, px0, px1, 1, xB0, xB1);
#define BNB(i) {                                                             \
    xB0.v##i = (xB0.v##i - m4[8 + i]) * rg4[8 + i] + bt4[8 + i];             \
    sa0 += xB0.v##i * xB0.v##i; v4f r_ = vrelu(xB0.v##i); ra0 += r_ * r_;    \
    xB1.v##i = (xB1.v##i - m4[8 + i]) * rg4[8 + i] + bt4[8 + i];             \
    sa1 += xB1.v##i * xB1.v##i; v4f p_ = vrelu(xB1.v##i); ra1 += p_ * p_; }
  EACH8(BNB)
#undef BNB
  gl[wid * 64 + lane]       = out_scale(hsum(sa0), hsum(ra0));
  gl[256 + wid * 64 + lane] = out_scale(hsum(sa1), hsum(ra1));
  __builtin_amdgcn_wave_barrier();

#define STOREROUND(ow, gp, choff)                                            \
  _Pragma("unroll") for (int j = 0; j < 8; j++) {                            \
    float g = (gp)[j * 8 + pr8];                                             \
    v4f v = vrelu(*(const v4f*)(rb + j * 8 * PADW2_)) * g;                   \
    __builtin_nontemporal_store(v, (ow) + (size_t)(j * 8 + pr8) * 16 + (choff) + qi); \
  }
  // round A0 (tile = BN'd xA0, S0 ch-quads 0..7)
  STOREROUND(outw0, gl_s0, 0)
  __builtin_amdgcn_wave_barrier();
  STAGE8(xA1);
  __builtin_amdgcn_wave_barrier();
  STOREROUND(outw1, gl_s1, 0)
  __builtin_amdgcn_wave_barrier();
  STAGE8(xB0);
  __builtin_amdgcn_wave_barrier();
  STOREROUND(outw0, gl_s0, 8)
  __builtin_amdgcn_wave_barrier();
  STAGE8(xB1);
  __builtin_amdgcn_wave_barrier();
  STOREROUND(outw1, gl_s1, 8)
#undef STOREROUND
}

// ---------------------------------------------------------------------------
extern "C" void kernel_launch(void* const* d_in, const int* in_sizes, int n_in,
                              void* d_out, int out_size, void* d_ws, size_t ws_size,
                              hipStream_t stream) {
  const float* x     = (const float*)d_in[0];  // [16,3,224,224]
  const float* wgt   = (const float*)d_in[1];  // [3,3,3,64] HWIO
  const float* bias  = (const float*)d_in[2];  // [64]
  const float* gamma = (const float*)d_in[3];  // [64]
  const float* beta  = (const float*)d_in[4];  // [64]
  float* out = (float*)d_out;                  // [16,224,224,64]

  char* ws = (char*)d_ws;
  float4* u0p      = (float4*)ws;                                           // 13,075,456 B
  float*  partials = (float*)(ws + (size_t)NPAD_ * 16);                     //    802,816 B
  float*  stats    = (float*)(ws + (size_t)NPAD_ * 16 + (size_t)NBLK2_ * 128 * 4); // 512 B

  hipLaunchKernelGGL(k0_transform, dim3((NPAD_ + 255) / 256), dim3(256), 0, stream, x, u0p);
  hipLaunchKernelGGL(k1_stats,     dim3(NBLK2_),              dim3(256), 0, stream, u0p, wgt, bias, partials);
  hipLaunchKernelGGL(k2_finalize,  dim3(64),                  dim3(256), 0, stream, partials, gamma, stats);
  hipLaunchKernelGGL(k3_final,     dim3(NBLK2_),              dim3(256), 0, stream, u0p, wgt, bias, stats, beta, out);
}